// Round 3
// baseline (1247.681 us; speedup 1.0000x reference)
//
#include <hip/hip_runtime.h>

// LSTM: B=512, T=1000, IN=39, H=64, OUT=48, gate order i,f,g,o.
// One block per batch row; thread = gate index (4H=256 threads).
// R5/R6:
//   (a) h-broadcast via SGPRs: each wave does ONE lane-distinct ds_read_b32
//       of h, then v_readlane -> SGPR, and the 64 hh-FMAs use the free SGPR
//       broadcast operand. Kills 16 uniform ds_read_b128 per thread per step
//       (the LDS return network was the limiting pipe: ~1660cy/CU/step).
//   (b) occupancy attrs amdgpu_waves_per_eu(2,2) WITH max (launch_bounds'
//       min-only form let the allocator target ~6 waves/EU -> 84-VGPR budget
//       -> weight spills). Grid gives exactly 2 blocks/CU, so (2,2) is free.
//   (c) role split: wave0 = cell update, wave1 = x staging, waves1-3 = output
//       projection.
//   R6: resubmit of R5 (infra failure, kernel never ran); pin asm tidied.

#define BB 512
#define TT 1000
#define INF 39
#define HH 64
#define OUTF 48
#define G4 (4 * HH)

typedef float v2f __attribute__((ext_vector_type(2)));

// ---- repeat lists ----
#define Q10(M) M(0) M(1) M(2) M(3) M(4) M(5) M(6) M(7) M(8) M(9)
#define Q16(M) M(0) M(1) M(2) M(3) M(4) M(5) M(6) M(7) \
               M(8) M(9) M(10) M(11) M(12) M(13) M(14) M(15)

__global__ __attribute__((amdgpu_flat_work_group_size(256, 256),
                          amdgpu_waves_per_eu(2, 2)))
void lstm_fused_kernel(
    const float* __restrict__ x,      // [B,T,IN]
    const float* __restrict__ W_ih,   // [4H, IN]
    const float* __restrict__ W_hh,   // [4H, H]
    const float* __restrict__ b_ih,   // [4H]
    const float* __restrict__ b_hh,   // [4H]
    const float* __restrict__ W_out,  // [OUT, H]
    const float* __restrict__ b_out,  // [OUT]
    float* __restrict__ out)          // [B,T,OUT]
{
    const int b = blockIdx.x;
    const int tid = threadIdx.x;          // gate index in [0,256)
    const int lane = tid & 63;
    const int wav = tid >> 6;             // 0=i,1=f,2=g,3=o

    __shared__ float xs[40];              // x_t broadcast (padded, xs[39]=0)
    __shared__ float hs[HH];              // h_t broadcast
    __shared__ float act[G4];             // gate activations

    // ---- one-time: weights into NAMED, PINNED registers ----
    const float* wih_ptr = W_ih + tid * INF;
#define LOAD_IH4(q) v2f wiA##q, wiB##q; \
    wiA##q.x = wih_ptr[4*(q)]; \
    wiA##q.y = (4*(q)+1 < INF) ? wih_ptr[4*(q)+1] : 0.f; \
    wiB##q.x = (4*(q)+2 < INF) ? wih_ptr[4*(q)+2] : 0.f; \
    wiB##q.y = (4*(q)+3 < INF) ? wih_ptr[4*(q)+3] : 0.f; \
    asm volatile("" : "+v"(wiA##q)); \
    asm volatile("" : "+v"(wiB##q));
    Q10(LOAD_IH4)

    const float4* wh4p = (const float4*)(W_hh + tid * HH);  // 256B-aligned
#define LOAD_HH4(i) const float4 whq##i = wh4p[i]; \
    v2f whA##i = {whq##i.x, whq##i.y}; \
    v2f whB##i = {whq##i.z, whq##i.w}; \
    asm volatile("" : "+v"(whA##i)); \
    asm volatile("" : "+v"(whB##i));
    Q16(LOAD_HH4)

    float bias = b_ih[tid] + b_hh[tid];
    asm volatile("" : "+v"(bias));

    // output-projection slice: waves 1-3, ot = tid-64 in [0,192)
    // o = ot>>2 in [0,48), p = ot&3 -> 16 weights each
    const int ot = tid - 64;
    const int o = ot >> 2;
    const int p = ot & 3;
    v2f woA0, woB0, woA1, woB1, woA2, woB2, woA3, woB3;
    float bo = 0.f;
    if (tid >= 64) {
        const float4* wop = (const float4*)(W_out + o * HH + p * 16); // 64B-aligned
        const float4 q0 = wop[0], q1 = wop[1], q2 = wop[2], q3 = wop[3];
        woA0 = (v2f){q0.x, q0.y}; woB0 = (v2f){q0.z, q0.w};
        woA1 = (v2f){q1.x, q1.y}; woB1 = (v2f){q1.z, q1.w};
        woA2 = (v2f){q2.x, q2.y}; woB2 = (v2f){q2.z, q2.w};
        woA3 = (v2f){q3.x, q3.y}; woB3 = (v2f){q3.z, q3.w};
        bo = b_out[o];
    } else {
        woA0 = woB0 = woA1 = woB1 = (v2f){0.f, 0.f};
        woA2 = woB2 = woA3 = woB3 = (v2f){0.f, 0.f};
    }
    asm volatile("" : "+v"(woA0)); asm volatile("" : "+v"(woB0));
    asm volatile("" : "+v"(woA1)); asm volatile("" : "+v"(woB1));
    asm volatile("" : "+v"(woA2)); asm volatile("" : "+v"(woB2));
    asm volatile("" : "+v"(woA3)); asm volatile("" : "+v"(woB3));
    asm volatile("" : "+v"(bo));

    float c = 0.f;                        // cell state, owned by wave 0
    const size_t x_base = (size_t)b * TT * INF;
    const size_t out_base = (size_t)b * TT * OUTF;

    if (tid < HH) hs[tid] = 0.f;
    if (wav == 1 && lane < INF) xs[lane] = x[x_base + lane];
    if (wav == 1 && lane == INF) xs[INF] = 0.f;
    float xreg = (wav == 1 && lane < INF) ? x[x_base + INF + lane] : 0.f; // x_1

    __syncthreads();                      // xs=x_0, hs=0 ready

    const float4* xs4 = (const float4*)xs;
    const float4* hs4 = (const float4*)hs;

    for (int t = 0; t < TT; ++t) {
        // ---- x part: uniform LDS b128 reads, packed FMAs ----
        v2f xaA = {bias, 0.f};
        v2f xaB = {0.f, 0.f};
#define FMA_IH4(q) { const float4 xv = xs4[q]; \
        const v2f xA = {xv.x, xv.y}; const v2f xB = {xv.z, xv.w}; \
        xaA += xA * wiA##q; xaB += xB * wiB##q; }
        Q10(FMA_IH4)

        // ---- h part: one lane-distinct ds_read + SGPR broadcast FMAs ----
        const float hval = hs[lane];                  // lane l holds h[l]
        const int hbits = __float_as_int(hval);
        float a0 = 0.f, a1 = 0.f, a2 = 0.f, a3 = 0.f;
#define RLF(j) __int_as_float(__builtin_amdgcn_readlane(hbits, (j)))
#define FMA_HH4(i, J) { \
        a0 = fmaf(RLF((J) + 0), whA##i.x, a0); \
        a1 = fmaf(RLF((J) + 1), whA##i.y, a1); \
        a2 = fmaf(RLF((J) + 2), whB##i.x, a2); \
        a3 = fmaf(RLF((J) + 3), whB##i.y, a3); }
        FMA_HH4(0, 0)   FMA_HH4(1, 4)   FMA_HH4(2, 8)   FMA_HH4(3, 12)
        FMA_HH4(4, 16)  FMA_HH4(5, 20)  FMA_HH4(6, 24)  FMA_HH4(7, 28)
        FMA_HH4(8, 32)  FMA_HH4(9, 36)  FMA_HH4(10, 40) FMA_HH4(11, 44)
        FMA_HH4(12, 48) FMA_HH4(13, 52) FMA_HH4(14, 56) FMA_HH4(15, 60)

        const float acc = ((xaA.x + xaA.y) + (xaB.x + xaB.y))
                        + ((a0 + a1) + (a2 + a3));

        float a;
        if (wav == 2) {                   // tanh gate (wave-uniform branch)
            a = 2.f / (1.f + __expf(-2.f * acc)) - 1.f;
        } else {                          // sigmoid
            a = 1.f / (1.f + __expf(-acc));
        }
        act[tid] = a;
        __syncthreads();                  // A: act ready; xs/hs reads done

        if (wav == 1) {
            // stage x_{t+1}; refill prefetch with x_{t+2}
            if (lane < INF) {
                xs[lane] = xreg;
                if (t + 2 < TT) xreg = x[x_base + (size_t)(t + 2) * INF + lane];
            }
        } else if (wav == 0) {
            const float ig = act[lane];
            const float fg = act[HH + lane];
            const float gg = act[2 * HH + lane];
            const float og = act[3 * HH + lane];
            c = fg * c + ig * gg;
            const float th = 2.f / (1.f + __expf(-2.f * c)) - 1.f;
            hs[lane] = og * th;
        }
        __syncthreads();                  // B: hs = h_t, xs = x_{t+1}

        // ---- output projection (waves 1-3): y = sigmoid(h . Wout_row + b) ----
        if (tid >= 64) {
            const float4 h0 = hs4[p * 4 + 0];
            const float4 h1 = hs4[p * 4 + 1];
            const float4 h2 = hs4[p * 4 + 2];
            const float4 h3 = hs4[p * 4 + 3];
            v2f sA = {0.f, 0.f}, sB = {0.f, 0.f};
            { const v2f a2 = {h0.x, h0.y}; const v2f b2 = {h0.z, h0.w};
              sA += a2 * woA0; sB += b2 * woB0; }
            { const v2f a2 = {h1.x, h1.y}; const v2f b2 = {h1.z, h1.w};
              sA += a2 * woA1; sB += b2 * woB1; }
            { const v2f a2 = {h2.x, h2.y}; const v2f b2 = {h2.z, h2.w};
              sA += a2 * woA2; sB += b2 * woB2; }
            { const v2f a2 = {h3.x, h3.y}; const v2f b2 = {h3.z, h3.w};
              sA += a2 * woA3; sB += b2 * woB3; }
            float s = (sA.x + sA.y) + (sB.x + sB.y);
            s += __shfl_xor(s, 1, 64);
            s += __shfl_xor(s, 2, 64);
            if (p == 0) {
                const float y = 1.f / (1.f + __expf(-(s + bo)));
                __builtin_nontemporal_store(y, &out[out_base + (size_t)t * OUTF + o]);
            }
        }
    }
}

extern "C" void kernel_launch(void* const* d_in, const int* in_sizes, int n_in,
                              void* d_out, int out_size, void* d_ws, size_t ws_size,
                              hipStream_t stream) {
    const float* x     = (const float*)d_in[0];
    const float* W_ih  = (const float*)d_in[1];
    const float* W_hh  = (const float*)d_in[2];
    const float* b_ih  = (const float*)d_in[3];
    const float* b_hh  = (const float*)d_in[4];
    const float* W_out = (const float*)d_in[5];
    const float* b_out = (const float*)d_in[6];
    float* out = (float*)d_out;

    lstm_fused_kernel<<<dim3(BB), dim3(G4), 0, stream>>>(
        x, W_ih, W_hh, b_ih, b_hh, W_out, b_out, out);
}

// Round 4
// 967.131 us; speedup vs baseline: 1.2901x; 1.2901x over previous
//
#include <hip/hip_runtime.h>

// LSTM: B=512, T=1000, IN=39, H=64, OUT=48, gate order i,f,g,o.
// R7: 2-wave producer/consumer, ONE batch row per 128-thread block.
//   Wave B (recurrent): lane l owns gate rows {l,64+l,128+l,192+l} and c_l,h_l.
//     W_hh (256 floats) in registers. Gates computed in-lane -> no act[] LDS,
//     no wave0-only serial phase, ONE barrier/step (was 2 + act round trip).
//     h broadcast: write h_l, read back 16 uniform b128 BEFORE the barrier
//     (latency hides under barrier + next xg read).
//   Wave A (producer): xg_{t+1} = bias + x_{t+1} . W_ih into LDS double
//     buffer; output projection + store for h_{t-1} (pipelined off the
//     critical wave). Arrives early at every barrier.
//   Register budget via __launch_bounds__(128, 1) (1 wave/EU -> 512 VGPRs).
//   R4/R6 lesson: VGPR_Count stuck at 88 -> waves_per_eu attr was ignored and
//   weights spilled to scratch; this round uses the documented launch_bounds
//   form and disjoint per-branch loops so A/B register sets overlap.

#define BB 512
#define TT 1000
#define INF 39
#define HH 64
#define OUTF 48

typedef float v2f __attribute__((ext_vector_type(2)));

#define Q10(M) M(0) M(1) M(2) M(3) M(4) M(5) M(6) M(7) M(8) M(9)
#define Q16(M) M(0) M(1) M(2) M(3) M(4) M(5) M(6) M(7) \
               M(8) M(9) M(10) M(11) M(12) M(13) M(14) M(15)

__global__ __launch_bounds__(128, 1)
void lstm_pc_kernel(const float* __restrict__ x,      // [B,T,IN]
                    const float* __restrict__ W_ih,   // [4H, IN]
                    const float* __restrict__ W_hh,   // [4H, H]
                    const float* __restrict__ b_ih,   // [4H]
                    const float* __restrict__ b_hh,   // [4H]
                    const float* __restrict__ W_out,  // [OUT, H]
                    const float* __restrict__ b_out,  // [OUT]
                    float* __restrict__ out)          // [B,T,OUT]
{
    const int b    = blockIdx.x;
    const int lane = threadIdx.x & 63;
    const int wav  = threadIdx.x >> 6;   // 0 = recurrent B, 1 = producer A

    __shared__ float xs[40];             // x_t broadcast (padded, xs[39]=0)
    __shared__ float xgb[2][4 * HH];     // xg double buffer [buf][g*64+l]
    __shared__ float hsb[2][HH];         // h double buffer

    const size_t x_base   = (size_t)b * TT * INF;
    const size_t out_base = (size_t)b * TT * OUTF;

    if (wav == 1) {
        // ======================= producer wave A =======================
        const int m = lane;

        // ---- W_ih rows {m, 64+m, 128+m, 192+m}, padded to 40 ----
#define LIH(g, q) v2f wiA##g##_##q, wiB##g##_##q; { \
        const float* wp_ = W_ih + ((g) * HH + m) * INF; \
        wiA##g##_##q.x = wp_[4*(q)]; \
        wiA##g##_##q.y = (4*(q)+1 < INF) ? wp_[4*(q)+1] : 0.f; \
        wiB##g##_##q.x = (4*(q)+2 < INF) ? wp_[4*(q)+2] : 0.f; \
        wiB##g##_##q.y = (4*(q)+3 < INF) ? wp_[4*(q)+3] : 0.f; }
#define LIH0(q) LIH(0, q)
#define LIH1(q) LIH(1, q)
#define LIH2(q) LIH(2, q)
#define LIH3(q) LIH(3, q)
        Q10(LIH0) Q10(LIH1) Q10(LIH2) Q10(LIH3)

        const float bg0 = b_ih[0*HH+m] + b_hh[0*HH+m];
        const float bg1 = b_ih[1*HH+m] + b_hh[1*HH+m];
        const float bg2 = b_ih[2*HH+m] + b_hh[2*HH+m];
        const float bg3 = b_ih[3*HH+m] + b_hh[3*HH+m];

        // ---- W_out row m (m<48): 64 floats ----
#define DWO(k) v2f woA##k = {0.f, 0.f}, woB##k = {0.f, 0.f};
        Q16(DWO)
        float bo = 0.f;
        if (m < OUTF) {
            const float4* wp_ = (const float4*)(W_out + m * HH); // 256B-aligned
#define LWO(k) { const float4 q_ = wp_[k]; \
            woA##k = (v2f){q_.x, q_.y}; woB##k = (v2f){q_.z, q_.w}; }
            Q16(LWO)
            bo = b_out[m];
        }

        // ---- macros ----
#define XQ(q) { const float4 xq_ = xs4_[q]; \
        const v2f xA_ = {xq_.x, xq_.y}, xB_ = {xq_.z, xq_.w}; \
        a0A += xA_ * wiA0_##q; a0B += xB_ * wiB0_##q; \
        a1A += xA_ * wiA1_##q; a1B += xB_ * wiB1_##q; \
        a2A += xA_ * wiA2_##q; a2B += xB_ * wiB2_##q; \
        a3A += xA_ * wiA3_##q; a3B += xB_ * wiB3_##q; }

#define XG_COMPUTE(BUF) { \
        const float4* xs4_ = (const float4*)xs; \
        v2f a0A = {bg0, 0.f}, a0B = {0.f, 0.f}; \
        v2f a1A = {bg1, 0.f}, a1B = {0.f, 0.f}; \
        v2f a2A = {bg2, 0.f}, a2B = {0.f, 0.f}; \
        v2f a3A = {bg3, 0.f}, a3B = {0.f, 0.f}; \
        Q10(XQ) \
        xgb[BUF][0*HH+m] = (a0A.x+a0A.y)+(a0B.x+a0B.y); \
        xgb[BUF][1*HH+m] = (a1A.x+a1A.y)+(a1B.x+a1B.y); \
        xgb[BUF][2*HH+m] = (a2A.x+a2A.y)+(a2B.x+a2B.y); \
        xgb[BUF][3*HH+m] = (a3A.x+a3A.y)+(a3B.x+a3B.y); }

#define OQ(k) { const float4 hq_ = hv_[k]; \
        sA += (v2f){hq_.x, hq_.y} * woA##k; \
        sB += (v2f){hq_.z, hq_.w} * woB##k; }

#define OUTPROJ(TIDX) { \
        const float4* hv_ = (const float4*)hsb[(TIDX) & 1]; \
        v2f sA = {0.f, 0.f}, sB = {0.f, 0.f}; \
        Q16(OQ) \
        if (m < OUTF) { \
            const float s_ = (sA.x+sA.y)+(sB.x+sB.y) + bo; \
            const float y_ = 1.f / (1.f + __expf(-s_)); \
            __builtin_nontemporal_store(y_, \
                &out[out_base + (size_t)(TIDX) * OUTF + m]); } }

        // ---- prologue: xs = x_0, xg_0 -> buf 0 ----
        if (m < INF)  xs[m]   = x[x_base + m];
        if (m == INF) xs[INF] = 0.f;
        float xreg = (m < INF) ? x[x_base + INF + m] : 0.f;  // x_1
        XG_COMPUTE(0)
        __syncthreads();

        for (int t = 0; t < TT; ++t) {
            // stage x_{t+1}; issue x_{t+2} prefetch EARLY (barrier drains vmcnt)
            if (t + 1 < TT) {
                if (m < INF) {
                    xs[m] = xreg;
                    if (t + 2 < TT) xreg = x[x_base + (size_t)(t + 2) * INF + m];
                }
            }
            // output projection for h_{t-1} (store issues early, acks hide)
            if (t >= 1) OUTPROJ(t - 1)
            // xg_{t+1} into buf (t+1)&1
            if (t + 1 < TT) XG_COMPUTE((t + 1) & 1)
            __syncthreads();
        }
        OUTPROJ(TT - 1)

    } else {
        // ======================= recurrent wave B =======================
        // W_hh rows {lane, 64+lane, 128+lane, 192+lane}: 256 floats in regs
#define LHH(g, k) v2f whA##g##_##k, whB##g##_##k; { \
        const float4 q_ = ((const float4*)(W_hh + ((g)*HH + lane) * HH))[k]; \
        whA##g##_##k = (v2f){q_.x, q_.y}; whB##g##_##k = (v2f){q_.z, q_.w}; }
#define LHH0(k) LHH(0, k)
#define LHH1(k) LHH(1, k)
#define LHH2(k) LHH(2, k)
#define LHH3(k) LHH(3, k)
        Q16(LHH0) Q16(LHH1) Q16(LHH2) Q16(LHH3)

        // h_{t-1} broadcast registers (loop-carried), start at h_{-1}=0
#define DNH(k) float4 nh##k = make_float4(0.f, 0.f, 0.f, 0.f);
        Q16(DNH)

        float c = 0.f;
        __syncthreads();                  // matches A prologue barrier

#define HQ(k) { const v2f hA_ = {nh##k.x, nh##k.y}, hB_ = {nh##k.z, nh##k.w}; \
        a0A += hA_ * whA0_##k; a0B += hB_ * whB0_##k; \
        a1A += hA_ * whA1_##k; a1B += hB_ * whB1_##k; \
        a2A += hA_ * whA2_##k; a2B += hB_ * whB2_##k; \
        a3A += hA_ * whA3_##k; a3B += hB_ * whB3_##k; }

        for (int t = 0; t < TT; ++t) {
            const int cb = t & 1;
            // xg reads issue now, consumed only after the 128 FMAs
            const float xg0_ = xgb[cb][0*HH + lane];
            const float xg1_ = xgb[cb][1*HH + lane];
            const float xg2_ = xgb[cb][2*HH + lane];
            const float xg3_ = xgb[cb][3*HH + lane];

            v2f a0A = {0.f,0.f}, a0B = {0.f,0.f};
            v2f a1A = {0.f,0.f}, a1B = {0.f,0.f};
            v2f a2A = {0.f,0.f}, a2B = {0.f,0.f};
            v2f a3A = {0.f,0.f}, a3B = {0.f,0.f};
            Q16(HQ)

            const float pi_ = (a0A.x+a0A.y)+(a0B.x+a0B.y) + xg0_;
            const float pf_ = (a1A.x+a1A.y)+(a1B.x+a1B.y) + xg1_;
            const float pg_ = (a2A.x+a2A.y)+(a2B.x+a2B.y) + xg2_;
            const float po_ = (a3A.x+a3A.y)+(a3B.x+a3B.y) + xg3_;

            const float si = 1.f / (1.f + __expf(-pi_));
            const float sf = 1.f / (1.f + __expf(-pf_));
            const float tg = 2.f / (1.f + __expf(-2.f * pg_)) - 1.f;
            const float so = 1.f / (1.f + __expf(-po_));

            c = fmaf(sf, c, si * tg);
            const float th = 2.f / (1.f + __expf(-2.f * c)) - 1.f;
            const float hN = so * th;

            hsb[cb][lane] = hN;           // publish h_t
            // read back full h_t for next step BEFORE the barrier
            const float4* hv_ = (const float4*)hsb[cb];
#define RNH(k) nh##k = hv_[k];
            Q16(RNH)
            __syncthreads();
        }
    }
}

extern "C" void kernel_launch(void* const* d_in, const int* in_sizes, int n_in,
                              void* d_out, int out_size, void* d_ws, size_t ws_size,
                              hipStream_t stream) {
    const float* x     = (const float*)d_in[0];
    const float* W_ih  = (const float*)d_in[1];
    const float* W_hh  = (const float*)d_in[2];
    const float* b_ih  = (const float*)d_in[3];
    const float* b_hh  = (const float*)d_in[4];
    const float* W_out = (const float*)d_in[5];
    const float* b_out = (const float*)d_in[6];
    float* out = (float*)d_out;

    lstm_pc_kernel<<<dim3(BB), dim3(128), 0, stream>>>(
        x, W_ih, W_hh, b_ih, b_hh, W_out, b_out, out);
}

// Round 5
// 871.688 us; speedup vs baseline: 1.4313x; 1.1095x over previous
//
#include <hip/hip_runtime.h>

// LSTM: B=512, T=1000, IN=39, H=64, OUT=48, gate order i,f,g,o.
// R8: split-K wave specialization, one batch row per 256-thread block.
//   R7 post-mortem: VGPR_Count=172 << 256 needed -> compiler rematerialized
//   W_hh from memory every step = 128KB/CU/step via L2 @ ~58B/cy = ~2200cy
//   == measured step time. Lesson: allocator refuses >~172 live VGPRs.
//   This round: per-lane weights = 120 floats (fits the granted budget).
//   Wave w owns k-slice [16w,16w+16) of W_hh and i-slice [10w,10w+10) of
//   W_ih for ALL 256 gate rows + k-slice of W_out for the fused out-proj.
//   Per step: all waves FMA vs their UNIFORM h/x slice (broadcast LDS reads)
//   -> float4 gate-partial exchange -> wave0: reduce+activations+c,h;
//   wave1: y reduce+sigmoid+store (y lags one step); wave2: x staging.
//   2 barriers/step; tails on different SIMDs; 2 blocks/CU interleave.

#define BB 512
#define TT 1000
#define INF 39
#define HH 64
#define OUTF 48

typedef float v2f __attribute__((ext_vector_type(2)));

__device__ __forceinline__ float sigf(float v) { return 1.f / (1.f + __expf(-v)); }
__device__ __forceinline__ float tanhx(float v) { return 2.f / (1.f + __expf(-2.f * v)) - 1.f; }

__global__ __launch_bounds__(256, 2)
void lstm_splitk(const float* __restrict__ x,      // [B,T,IN]
                 const float* __restrict__ W_ih,   // [4H, IN]
                 const float* __restrict__ W_hh,   // [4H, H]
                 const float* __restrict__ b_ih,   // [4H]
                 const float* __restrict__ b_hh,   // [4H]
                 const float* __restrict__ W_out,  // [OUT, H]
                 const float* __restrict__ b_out,  // [OUT]
                 float* __restrict__ out)          // [B,T,OUT]
{
    const int b    = blockIdx.x;
    const int lane = threadIdx.x & 63;
    const int wav  = threadIdx.x >> 6;   // k-slice owner, 0..3
    const int K0   = wav * 16;           // hidden slice [K0, K0+16)
    const int I0   = wav * 10;           // input  slice [I0, I0+10), 39 padded to 40

    __shared__ float  xs[40];            // x_t broadcast (xs[39] = 0)
    __shared__ float  hs[HH];            // h_{t} broadcast
    __shared__ float4 parts[4][64];      // gate partials [wave][lane] = (i,f,g,o)
    __shared__ float  yp[4][OUTF];       // y partials [wave][out]

    const size_t x_base   = (size_t)b * TT * INF;
    const size_t out_base = (size_t)b * TT * OUTF;

    // ---- one-time: weight slices into registers (120 floats/lane) ----
    float4 wh[4][4];                     // W_hh[g*64+lane][K0..K0+16)
#pragma unroll
    for (int g = 0; g < 4; ++g) {
        const float4* p = (const float4*)(W_hh + (g * HH + lane) * HH + K0); // 64B-aligned
        wh[g][0] = p[0]; wh[g][1] = p[1]; wh[g][2] = p[2]; wh[g][3] = p[3];
    }

    float wi[4][10];                     // W_ih[g*64+lane][I0..I0+10), OOB->0
#pragma unroll
    for (int g = 0; g < 4; ++g) {
        const float* p = W_ih + (g * HH + lane) * INF;
#pragma unroll
        for (int j = 0; j < 10; ++j) {
            const int i = I0 + j;
            wi[g][j] = (i < INF) ? p[i] : 0.f;
        }
    }

    float4 wo[4];                        // W_out[lane][K0..K0+16) for lane<48
    wo[0] = wo[1] = wo[2] = wo[3] = make_float4(0.f, 0.f, 0.f, 0.f);
    float bo = 0.f;
    if (lane < OUTF) {
        const float4* p = (const float4*)(W_out + lane * HH + K0);           // 64B-aligned
        wo[0] = p[0]; wo[1] = p[1]; wo[2] = p[2]; wo[3] = p[3];
        bo = b_out[lane];
    }

    float bg[4];                         // bias, consumed by wave 0's partial init
#pragma unroll
    for (int g = 0; g < 4; ++g) bg[g] = b_ih[g * HH + lane] + b_hh[g * HH + lane];

    // ---- prologue ----
    if (wav == 0) hs[lane] = 0.f;        // h_{-1} = 0
    if (wav == 2) {
        if (lane < INF) xs[lane] = x[x_base + lane];
        if (lane == INF) xs[INF] = 0.f;
    }
    float xreg = (wav == 2 && lane < INF) ? x[x_base + INF + lane] : 0.f;    // x_1
    float c = 0.f;                       // cell state, wave 0 lanes
    __syncthreads();

    for (int t = 0; t < TT; ++t) {
        // ---- FMA phase: all waves, uniform slice reads (LDS broadcast) ----
        const float4* hs4 = (const float4*)hs;
        const float4 hq0 = hs4[wav * 4 + 0];
        const float4 hq1 = hs4[wav * 4 + 1];
        const float4 hq2 = hs4[wav * 4 + 2];
        const float4 hq3 = hs4[wav * 4 + 3];

        float xv[10];
#pragma unroll
        for (int j = 0; j < 10; ++j) xv[j] = xs[I0 + j];

        float sg_[4];
#pragma unroll
        for (int g = 0; g < 4; ++g) {
            v2f aA = { (wav == 0) ? bg[g] : 0.f, 0.f };
            v2f aB = { 0.f, 0.f };
            aA += (v2f){hq0.x, hq0.y} * (v2f){wh[g][0].x, wh[g][0].y};
            aB += (v2f){hq0.z, hq0.w} * (v2f){wh[g][0].z, wh[g][0].w};
            aA += (v2f){hq1.x, hq1.y} * (v2f){wh[g][1].x, wh[g][1].y};
            aB += (v2f){hq1.z, hq1.w} * (v2f){wh[g][1].z, wh[g][1].w};
            aA += (v2f){hq2.x, hq2.y} * (v2f){wh[g][2].x, wh[g][2].y};
            aB += (v2f){hq2.z, hq2.w} * (v2f){wh[g][2].z, wh[g][2].w};
            aA += (v2f){hq3.x, hq3.y} * (v2f){wh[g][3].x, wh[g][3].y};
            aB += (v2f){hq3.z, hq3.w} * (v2f){wh[g][3].z, wh[g][3].w};
            aA += (v2f){xv[0], xv[1]} * (v2f){wi[g][0], wi[g][1]};
            aB += (v2f){xv[2], xv[3]} * (v2f){wi[g][2], wi[g][3]};
            aA += (v2f){xv[4], xv[5]} * (v2f){wi[g][4], wi[g][5]};
            aB += (v2f){xv[6], xv[7]} * (v2f){wi[g][6], wi[g][7]};
            aA += (v2f){xv[8], xv[9]} * (v2f){wi[g][8], wi[g][9]};
            sg_[g] = (aA.x + aA.y) + (aB.x + aB.y);
        }

        // y-partial for y_{t-1}: this wave's k-slice of h_{t-1} . W_out
        float yv;
        {
            v2f yA = {0.f, 0.f}, yB = {0.f, 0.f};
            yA += (v2f){hq0.x, hq0.y} * (v2f){wo[0].x, wo[0].y};
            yB += (v2f){hq0.z, hq0.w} * (v2f){wo[0].z, wo[0].w};
            yA += (v2f){hq1.x, hq1.y} * (v2f){wo[1].x, wo[1].y};
            yB += (v2f){hq1.z, hq1.w} * (v2f){wo[1].z, wo[1].w};
            yA += (v2f){hq2.x, hq2.y} * (v2f){wo[2].x, wo[2].y};
            yB += (v2f){hq2.z, hq2.w} * (v2f){wo[2].z, wo[2].w};
            yA += (v2f){hq3.x, hq3.y} * (v2f){wo[3].x, wo[3].y};
            yB += (v2f){hq3.z, hq3.w} * (v2f){wo[3].z, wo[3].w};
            yv = (yA.x + yA.y) + (yB.x + yB.y);
        }

        if (wav != 0) parts[wav][lane] = make_float4(sg_[0], sg_[1], sg_[2], sg_[3]);
        if (wav != 1 && lane < OUTF) yp[wav][lane] = yv;
        __syncthreads();                  // A: partials ready; slice reads done

        if (wav == 0) {
            // reduce gate partials, activations, state update, publish h_t
            const float4 p1 = parts[1][lane];
            const float4 p2 = parts[2][lane];
            const float4 p3 = parts[3][lane];
            const float gi = sg_[0] + p1.x + p2.x + p3.x;
            const float gf = sg_[1] + p1.y + p2.y + p3.y;
            const float gg = sg_[2] + p1.z + p2.z + p3.z;
            const float go = sg_[3] + p1.w + p2.w + p3.w;
            const float si = sigf(gi);
            const float sf = sigf(gf);
            const float tg = tanhx(gg);
            const float so = sigf(go);
            c = fmaf(sf, c, si * tg);
            hs[lane] = so * tanhx(c);
        } else if (wav == 1) {
            // reduce y partials for y_{t-1}, store
            if (t >= 1 && lane < OUTF) {
                const float y = sigf(yv + yp[0][lane] + yp[2][lane] + yp[3][lane] + bo);
                __builtin_nontemporal_store(y, &out[out_base + (size_t)(t - 1) * OUTF + lane]);
            }
        } else if (wav == 2) {
            // stage x_{t+1}; refill prefetch with x_{t+2}
            if (lane < INF) {
                xs[lane] = xreg;
                if (t + 2 < TT) xreg = x[x_base + (size_t)(t + 2) * INF + lane];
            }
        }
        __syncthreads();                  // B: hs = h_t, xs = x_{t+1}
    }

    // ---- epilogue: y_{T-1} from h_{T-1} ----
    {
        const float4* hs4 = (const float4*)hs;
        const float4 hq0 = hs4[wav * 4 + 0];
        const float4 hq1 = hs4[wav * 4 + 1];
        const float4 hq2 = hs4[wav * 4 + 2];
        const float4 hq3 = hs4[wav * 4 + 3];
        v2f yA = {0.f, 0.f}, yB = {0.f, 0.f};
        yA += (v2f){hq0.x, hq0.y} * (v2f){wo[0].x, wo[0].y};
        yB += (v2f){hq0.z, hq0.w} * (v2f){wo[0].z, wo[0].w};
        yA += (v2f){hq1.x, hq1.y} * (v2f){wo[1].x, wo[1].y};
        yB += (v2f){hq1.z, hq1.w} * (v2f){wo[1].z, wo[1].w};
        yA += (v2f){hq2.x, hq2.y} * (v2f){wo[2].x, wo[2].y};
        yB += (v2f){hq2.z, hq2.w} * (v2f){wo[2].z, wo[2].w};
        yA += (v2f){hq3.x, hq3.y} * (v2f){wo[3].x, wo[3].y};
        yB += (v2f){hq3.z, hq3.w} * (v2f){wo[3].z, wo[3].w};
        const float yvv = (yA.x + yA.y) + (yB.x + yB.y);
        if (wav != 1 && lane < OUTF) yp[wav][lane] = yvv;
        __syncthreads();
        if (wav == 1 && lane < OUTF) {
            const float y = sigf(yvv + yp[0][lane] + yp[2][lane] + yp[3][lane] + bo);
            __builtin_nontemporal_store(y, &out[out_base + (size_t)(TT - 1) * OUTF + lane]);
        }
    }
}

extern "C" void kernel_launch(void* const* d_in, const int* in_sizes, int n_in,
                              void* d_out, int out_size, void* d_ws, size_t ws_size,
                              hipStream_t stream) {
    const float* x     = (const float*)d_in[0];
    const float* W_ih  = (const float*)d_in[1];
    const float* W_hh  = (const float*)d_in[2];
    const float* b_ih  = (const float*)d_in[3];
    const float* b_hh  = (const float*)d_in[4];
    const float* W_out = (const float*)d_in[5];
    const float* b_out = (const float*)d_in[6];
    float* out = (float*)d_out;

    lstm_splitk<<<dim3(BB), dim3(256), 0, stream>>>(
        x, W_ih, W_hh, b_ih, b_hh, W_out, b_out, out);
}